// Round 1
// baseline (394.051 us; speedup 1.0000x reference)
//
#include <hip/hip_runtime.h>

// Shapes fixed by setup_inputs(): b=8, s=4096, h=16, p=64, n=64, L=64.
// Reduction: out[b,h,p,n] = sum_t exp(Total(b,h) - P(b,h,t)) * X[b,t,h,p] * B[b,t,h,n]
// where P = inclusive prefix-sum of A over t, Total = P[s-1]. (Chunked scan telescopes.)

constexpr int Bn = 8;
constexpr int S  = 4096;
constexpr int H  = 16;
constexpr int P  = 64;
constexpr int N  = 64;

constexpr int NCH = 8;         // t-chunks per (b,h) pair
constexpr int TCH = S / NCH;   // 512 timesteps per chunk
constexpr int TB  = 32;        // timesteps staged per LDS buffer
constexpr int NIT = TCH / TB;  // 16 buffer iterations per block

// ---------------- Kernel 1: per-(b,h) prefix scan of A -> weights ----------------
// W[pair*S + t] = exp(Total - P_inclusive[t]),  pair = bb*H + hh
__global__ __launch_bounds__(256) void scan_weights(
    const float* __restrict__ A, float* __restrict__ W) {
  const int pair = blockIdx.x;         // 0..Bn*H-1
  const int bb = pair / H, hh = pair % H;
  const int tid = threadIdx.x;
  constexpr int TPT = S / 256;         // 16 elements per thread

  float vals[TPT];
  float local = 0.f;
  const int t0 = tid * TPT;
  #pragma unroll
  for (int i = 0; i < TPT; ++i) {
    float a = A[((size_t)bb * S + t0 + i) * H + hh];
    local += a;
    vals[i] = local;                   // inclusive within thread
  }

  __shared__ float sums[256];
  sums[tid] = local;
  __syncthreads();
  // Hillis-Steele inclusive scan over per-thread totals
  for (int off = 1; off < 256; off <<= 1) {
    float v = sums[tid];
    float add = (tid >= off) ? sums[tid - off] : 0.f;
    __syncthreads();
    sums[tid] = v + add;
    __syncthreads();
  }
  const float total = sums[255];
  const float excl  = sums[tid] - local;   // exclusive prefix for this thread

  float* Wp = W + (size_t)pair * S;
  #pragma unroll
  for (int i = 0; i < TPT; ++i) {
    Wp[t0 + i] = __expf(total - (excl + vals[i]));  // exponent <= 0 (A <= 0)
  }
}

// ---------------- Kernel 2: weighted outer-product accumulation ----------------
// One block per (pair, chunk). 256 threads = 4 waves.
// Each wave covers the full 64x64 output with 8x8 per-lane tiles; the 4 waves
// split the staged timesteps (tt % 4 == wid) and combine partials via LDS tree.
// Double-buffered LDS staging (32 rows of X and B per buffer), register prefetch,
// one barrier per 32 timesteps.
__global__ __launch_bounds__(256, 4) void outer_accum(
    const float* __restrict__ X, const float* __restrict__ Bm,
    const float* __restrict__ W, float* __restrict__ out) {
  // buffer layout (float4 units): [0..511] = X rows [32][16], [512..1023] = B rows [32][16]
  __shared__ float4 lds[2][1024];      // 32 KB total

  const int bid  = blockIdx.x;
  const int pair = bid / NCH;
  const int ch   = bid % NCH;
  const int tid  = threadIdx.x;
  const int lane = tid & 63;
  const int wid  = tid >> 6;           // wave id 0..3
  const int t_begin = ch * TCH;

  // compute mapping: lane covers an 8x8 tile of the 64x64 (p,n) output
  const int pr = (lane >> 3) * 8;      // p base
  const int nc = (lane & 7) * 8;       // n base

  // staging mapping: thread loads 4 float4 (2 X rows, 2 B rows)
  const int srow = tid >> 4;           // 0..15
  const int scol = (tid & 15) * 4;     // 0..60

  const int bb = pair / H, hh = pair % H;
  const float* Xp = X  + (size_t)bb * S * H * P + (size_t)hh * P + scol;
  const float* Bp = Bm + (size_t)bb * S * H * N + (size_t)hh * N + scol;
  const float* Wp = W + (size_t)pair * S;

  float4 rx0, rx1, rb0, rb1;
  float w0, w1;

  auto LOAD = [&](int t0) {
    const int ta = t0 + srow;
    const int tb = ta + 16;
    w0 = Wp[ta];
    w1 = Wp[tb];
    rx0 = *(const float4*)(Xp + (size_t)ta * (H * P));
    rx1 = *(const float4*)(Xp + (size_t)tb * (H * P));
    rb0 = *(const float4*)(Bp + (size_t)ta * (H * N));
    rb1 = *(const float4*)(Bp + (size_t)tb * (H * N));
  };
  auto STORE = [&](int buf) {
    float4 a = rx0; a.x *= w0; a.y *= w0; a.z *= w0; a.w *= w0;  // pre-scale X by decay
    float4 b = rx1; b.x *= w1; b.y *= w1; b.z *= w1; b.w *= w1;
    lds[buf][tid]       = a;   // X rows 0..15
    lds[buf][256 + tid] = b;   // X rows 16..31
    lds[buf][512 + tid] = rb0; // B rows 0..15
    lds[buf][768 + tid] = rb1; // B rows 16..31
  };

  float acc[8][8];
  #pragma unroll
  for (int i = 0; i < 8; ++i)
    #pragma unroll
    for (int k = 0; k < 8; ++k) acc[i][k] = 0.f;

  LOAD(t_begin);
  STORE(0);
  __syncthreads();

  for (int it = 0; it < NIT; ++it) {
    const int cur = it & 1;
    if (it + 1 < NIT) LOAD(t_begin + (it + 1) * TB);  // prefetch next tile (in flight during compute)

    const float* Xs = (const float*)&lds[cur][0];
    const float* Bs = (const float*)&lds[cur][512];
    #pragma unroll
    for (int j = 0; j < 8; ++j) {
      const int tt = (j << 2) | wid;                   // this wave's timestep in the buffer
      const float4 xa = *(const float4*)(Xs + tt * 64 + pr);
      const float4 xb = *(const float4*)(Xs + tt * 64 + pr + 4);
      const float4 ba = *(const float4*)(Bs + tt * 64 + nc);
      const float4 bc = *(const float4*)(Bs + tt * 64 + nc + 4);
      const float xs[8] = {xa.x, xa.y, xa.z, xa.w, xb.x, xb.y, xb.z, xb.w};
      const float bs[8] = {ba.x, ba.y, ba.z, ba.w, bc.x, bc.y, bc.z, bc.w};
      #pragma unroll
      for (int i = 0; i < 8; ++i)
        #pragma unroll
        for (int k = 0; k < 8; ++k)
          acc[i][k] = fmaf(xs[i], bs[k], acc[i][k]);
    }

    if (it + 1 < NIT) {
      STORE((it + 1) & 1);   // waits on prefetch loads; writes the other buffer
      __syncthreads();       // one barrier per 32 timesteps
    }
  }

  // ---- cross-wave reduction of the 4 t-phase partials (LDS tree) ----
  __syncthreads();                       // LDS reusable now
  float4* red = (float4*)&lds[0][0];     // 2048 float4 available

  if (wid & 1) {                         // waves 1,3 publish
    float4* r = red + ((wid >> 1) ? 1024 : 0) + lane;
    #pragma unroll
    for (int i = 0; i < 8; ++i) {
      r[(2 * i + 0) * 64] = make_float4(acc[i][0], acc[i][1], acc[i][2], acc[i][3]);
      r[(2 * i + 1) * 64] = make_float4(acc[i][4], acc[i][5], acc[i][6], acc[i][7]);
    }
  }
  __syncthreads();
  if (!(wid & 1)) {                      // waves 0,2 absorb
    const float4* r = red + ((wid >> 1) ? 1024 : 0) + lane;
    #pragma unroll
    for (int i = 0; i < 8; ++i) {
      const float4 v0 = r[(2 * i + 0) * 64];
      const float4 v1 = r[(2 * i + 1) * 64];
      acc[i][0] += v0.x; acc[i][1] += v0.y; acc[i][2] += v0.z; acc[i][3] += v0.w;
      acc[i][4] += v1.x; acc[i][5] += v1.y; acc[i][6] += v1.z; acc[i][7] += v1.w;
    }
  }
  __syncthreads();
  if (wid == 2) {                        // wave 2 publishes its sum
    float4* r = red + lane;
    #pragma unroll
    for (int i = 0; i < 8; ++i) {
      r[(2 * i + 0) * 64] = make_float4(acc[i][0], acc[i][1], acc[i][2], acc[i][3]);
      r[(2 * i + 1) * 64] = make_float4(acc[i][4], acc[i][5], acc[i][6], acc[i][7]);
    }
  }
  __syncthreads();
  if (wid == 0) {                        // wave 0 finalizes + atomically combines t-chunks
    const float4* r = red + lane;
    #pragma unroll
    for (int i = 0; i < 8; ++i) {
      const float4 v0 = r[(2 * i + 0) * 64];
      const float4 v1 = r[(2 * i + 1) * 64];
      acc[i][0] += v0.x; acc[i][1] += v0.y; acc[i][2] += v0.z; acc[i][3] += v0.w;
      acc[i][4] += v1.x; acc[i][5] += v1.y; acc[i][6] += v1.z; acc[i][7] += v1.w;
    }
    float* outp = out + (size_t)pair * P * N;  // out[b,h,p,n]
    #pragma unroll
    for (int i = 0; i < 8; ++i)
      #pragma unroll
      for (int k = 0; k < 8; ++k)
        atomicAdd(&outp[(size_t)(pr + i) * N + (nc + k)], acc[i][k]);
  }
}

extern "C" void kernel_launch(void* const* d_in, const int* in_sizes, int n_in,
                              void* d_out, int out_size, void* d_ws, size_t ws_size,
                              hipStream_t stream) {
  const float* X = (const float*)d_in[0];   // (b, s, h, p)
  const float* A = (const float*)d_in[1];   // (b, s, h)
  const float* B = (const float*)d_in[2];   // (b, s, h, n)
  float* out = (float*)d_out;               // (b, h, p, n)
  float* W   = (float*)d_ws;                // Bn*H*S floats = 2 MB scratch

  // out is poisoned 0xAA before every launch; atomics need zeros
  hipMemsetAsync(d_out, 0, (size_t)out_size * sizeof(float), stream);

  scan_weights<<<Bn * H, 256, 0, stream>>>(A, W);
  outer_accum<<<Bn * H * NCH, 256, 0, stream>>>(X, B, W, out);
}